// Round 7
// baseline (963.498 us; speedup 1.0000x reference)
//
#include <hip/hip_runtime.h>
#include <cstdint>

// SparseMLP: out = relu(relu(x@W1^T+b1)@W2^T+b2)@W3^T+b3
// M = N = K = 4096 per layer. fp32 in/out; fp16 MFMA internally.
//
// R11 vs R4-R10 (all GEMM ~121us, two different walls):
//  - 256^2 1-block/CU variants: low LDS traffic (4.2GB, 61us floor) but
//    barrier-locked convoy (read-drain 585 + MFMA 620 per phase = measured
//    4745 cyc/tile). Nothing co-resident to overlap with.
//  - R4 128^2: cross-block TLP overlaps pipes (m114) but 64x64 wave-tiles
//    -> 6.3GB LDS (91us floor).
// R11 = both proven elements: tile 128x256 (512 blocks), 256 thr / 4 waves
// (2x2, wave-tile 64x128, acc[4][8], FLOP/LDS-byte 42.7), SINGLE-buffer
// 48KB LDS -> 3 blocks/CU, 12 waves/CU. LDS 4.7GB (68us floor), MFMA 66us;
// stage-drain of one block hides under MFMA of the other two. Schedule is
// the R4-proven 2-barrier loop (compiler waitcnts, verified XOR-chunk
// swizzle + frag numerics). No setprio (m190: negative on multi-block).
// Converts unchanged from R6 (best total so far).

#define MATN 4096

typedef _Float16 half8 __attribute__((ext_vector_type(8)));
typedef float f32x4 __attribute__((ext_vector_type(4)));

// async global->LDS, 16B/lane. LDS dest = wave-uniform base + lane*16.
__device__ __forceinline__ void glds16(const void* g, void* l) {
    __builtin_amdgcn_global_load_lds(
        (const __attribute__((address_space(1))) char*)(uintptr_t)g,
        (__attribute__((address_space(3))) char*)(uintptr_t)l,
        16, 0, 0);
}

__device__ __forceinline__ void cvt_body(const float* __restrict__ in,
                                         _Float16* __restrict__ out, int n8) {
    for (int g = blockIdx.x * 256 + threadIdx.x; g < n8; g += gridDim.x * 256) {
        size_t i = (size_t)g * 8;
        float4 a = *(const float4*)(in + i);
        float4 b = *(const float4*)(in + i + 4);
        half8 o;
        o[0] = (_Float16)a.x; o[1] = (_Float16)a.y;
        o[2] = (_Float16)a.z; o[3] = (_Float16)a.w;
        o[4] = (_Float16)b.x; o[5] = (_Float16)b.y;
        o[6] = (_Float16)b.z; o[7] = (_Float16)b.w;
        *(half8*)(out + i) = o;
    }
}

__global__ __launch_bounds__(256)
void cvt_f16(const float* __restrict__ in, _Float16* __restrict__ out, int n8) {
    cvt_body(in, out, n8);
}

__global__ __launch_bounds__(256)
void cvt_f16_2(const float* __restrict__ i0, _Float16* __restrict__ o0,
               const float* __restrict__ i1, _Float16* __restrict__ o1, int n8) {
    cvt_body(blockIdx.y ? i1 : i0, blockIdx.y ? o1 : o0, n8);
}

__global__ __launch_bounds__(256)
void cvt_f16_4(const float* __restrict__ i0, _Float16* __restrict__ o0,
               const float* __restrict__ i1, _Float16* __restrict__ o1,
               const float* __restrict__ i2, _Float16* __restrict__ o2,
               const float* __restrict__ i3, _Float16* __restrict__ o3, int n8) {
    const float* in;
    _Float16* out;
    switch (blockIdx.y) {
        case 0: in = i0; out = o0; break;
        case 1: in = i1; out = o1; break;
        case 2: in = i2; out = o2; break;
        default: in = i3; out = o3; break;
    }
    cvt_body(in, out, n8);
}

// C[m][n] = sum_k A[m][k]*B[n][k] + bias[n] (optional ReLU).
// A,B: [4096][4096] f16 row-major (K-contig). 128x256 tile, BK=64,
// 4 waves (2x2), wave-tile 64x128, 2 k-halves per tile. Single-buffer 48KB.
#define MFMA_(d, x, y) d = __builtin_amdgcn_mfma_f32_16x16x32_f16(x, y, d, 0, 0, 0)

template <bool RELU, typename OutT>
__global__ __launch_bounds__(256, 3)
void gemm_bt(const _Float16* __restrict__ A, const _Float16* __restrict__ B,
             const float* __restrict__ bias, OutT* __restrict__ C) {
    __shared__ _Float16 sA[128 * 64];  // 16 KB, 128B rows, XOR-chunk swizzled
    __shared__ _Float16 sB[256 * 64];  // 32 KB

    const int tid  = threadIdx.x;
    const int lane = tid & 63;
    const int w    = tid >> 6;   // 4 waves
    const int wm   = w >> 1;     // 0..1: rows wm*64..+64
    const int wn   = w & 1;      // 0..1: cols wn*128..+128
    const int l16  = lane & 15;
    const int kq   = lane >> 4;  // 0..3

    // bijective XCD swizzle: 512 blocks, 512 % 8 == 0, chunks of 64
    const int bid   = blockIdx.y * 16 + blockIdx.x;
    const int sbid  = (bid & 7) * 64 + (bid >> 3);
    const int tileM = (sbid >> 4) * 128;  // 0..31
    const int tileN = (sbid & 15) * 256;  // 0..15

    f32x4 acc[4][8] = {};

    // staging: thread t -> row_in = t>>3 (0..31), slot = t&7.
    // LDS slot s of row r holds global 16B chunk s ^ (r&7); rows advance
    // 32/round (32%8==0 -> per-thread swizzle term round-invariant). R4-proven.
    const int rin = tid >> 3;
    const int gch = (tid & 7) ^ (rin & 7);
    const _Float16* Ap = A + (size_t)(tileM + rin) * MATN + gch * 8;
    const _Float16* Bp = B + (size_t)(tileN + rin) * MATN + gch * 8;
    const size_t rstep = (size_t)32 * MATN;  // rows between staging rounds

    char* sAl = (char*)sA + w * 1024;  // wave-uniform LDS bases (+lane*16)
    char* sBl = (char*)sB + w * 1024;

    // fragment read bases: row = frag_base + l16 (row&7 == l16&7),
    // wanted chunk kh*4+kq lives at slot (kh*4+kq)^(l16&7): 2-way/quarter = free.
    const int sl0 = kq ^ (l16 & 7);
    const int sl1 = sl0 ^ 4;
    const _Float16* rA0 = sA + (wm * 64 + l16) * 64 + sl0 * 8;
    const _Float16* rA1 = sA + (wm * 64 + l16) * 64 + sl1 * 8;
    const _Float16* rB0 = sB + (wn * 128 + l16) * 64 + sl0 * 8;
    const _Float16* rB1 = sB + (wn * 128 + l16) * 64 + sl1 * 8;

    for (int k0 = 0; k0 < MATN; k0 += 64) {
#pragma unroll
        for (int c = 0; c < 4; ++c) glds16(Ap + c * rstep, sAl + c * 4096);
#pragma unroll
        for (int c = 0; c < 8; ++c) glds16(Bp + c * rstep, sBl + c * 4096);
        Ap += 64; Bp += 64;
        __syncthreads();  // drains vmcnt (glds landed) + syncs waves

        half8 a[4], b[8];
        // k-half 0
#pragma unroll
        for (int mi = 0; mi < 4; ++mi) a[mi] = *(const half8*)(rA0 + mi * 1024);
#pragma unroll
        for (int ni = 0; ni < 8; ++ni) b[ni] = *(const half8*)(rB0 + ni * 1024);
#pragma unroll
        for (int mi = 0; mi < 4; ++mi)
#pragma unroll
            for (int ni = 0; ni < 8; ++ni) MFMA_(acc[mi][ni], a[mi], b[ni]);
        // k-half 1
#pragma unroll
        for (int mi = 0; mi < 4; ++mi) a[mi] = *(const half8*)(rA1 + mi * 1024);
#pragma unroll
        for (int ni = 0; ni < 8; ++ni) b[ni] = *(const half8*)(rB1 + ni * 1024);
#pragma unroll
        for (int mi = 0; mi < 4; ++mi)
#pragma unroll
            for (int ni = 0; ni < 8; ++ni) MFMA_(acc[mi][ni], a[mi], b[ni]);
        __syncthreads();  // all reads done before next tile's stage overwrites
    }

    // epilogue: C/D layout col = lane&15, row = (lane>>4)*4 + reg (m89)
#pragma unroll
    for (int ni = 0; ni < 8; ++ni) {
        const int gn = tileN + wn * 128 + ni * 16 + l16;
        const float bv = bias[gn];
#pragma unroll
        for (int mi = 0; mi < 4; ++mi) {
            const int gm = tileM + wm * 64 + mi * 16 + kq * 4;
#pragma unroll
            for (int r = 0; r < 4; ++r) {
                float v = acc[mi][ni][r] + bv;
                if (RELU) v = v > 0.f ? v : 0.f;
                C[(size_t)(gm + r) * MATN + gn] = (OutT)v;
            }
        }
    }
}

extern "C" void kernel_launch(void* const* d_in, const int* in_sizes, int n_in,
                              void* d_out, int out_size, void* d_ws, size_t ws_size,
                              hipStream_t stream) {
    const float* x  = (const float*)d_in[0];
    const float* W1 = (const float*)d_in[1];
    const float* b1 = (const float*)d_in[2];
    const float* W2 = (const float*)d_in[3];
    const float* b2 = (const float*)d_in[4];
    const float* W3 = (const float*)d_in[5];
    const float* b3 = (const float*)d_in[6];
    float* out = (float*)d_out;

    const size_t MAT = (size_t)MATN * MATN;
    const size_t HB  = MAT * 2;  // bytes per f16 matrix
    const int n8 = (int)(MAT / 8);
    dim3 ggrid(MATN / 256, MATN / 128);  // 16 x 32 = 512 blocks

    if (ws_size >= HB * 5) {
        // roomy path: all converts in one launch
        _Float16* xb = (_Float16*)d_ws;
        _Float16* w1 = (_Float16*)((char*)d_ws + HB);
        _Float16* w2 = (_Float16*)((char*)d_ws + HB * 2);
        _Float16* w3 = (_Float16*)((char*)d_ws + HB * 3);
        _Float16* h1 = (_Float16*)((char*)d_ws + HB * 4);
        _Float16* h2 = xb;  // xb dead after layer 1

        cvt_f16_4<<<dim3(2048, 4), 256, 0, stream>>>(x, xb, W1, w1, W2, w2,
                                                     W3, w3, n8);
        gemm_bt<true, _Float16><<<ggrid, 256, 0, stream>>>(xb, w1, b1, h1);
        gemm_bt<true, _Float16><<<ggrid, 256, 0, stream>>>(h1, w2, b2, h2);
        gemm_bt<false, float><<<ggrid, 256, 0, stream>>>(h2, w3, b3, out);
    } else {
        // 96MB fallback: shared per-layer W buffer
        _Float16* xb = (_Float16*)d_ws;
        _Float16* wb = (_Float16*)((char*)d_ws + HB);
        _Float16* h1 = (_Float16*)((char*)d_ws + HB * 2);
        _Float16* h2 = xb;

        cvt_f16_2<<<dim3(2048, 2), 256, 0, stream>>>(x, xb, W1, wb, n8);
        gemm_bt<true, _Float16><<<ggrid, 256, 0, stream>>>(xb, wb, b1, h1);
        cvt_f16<<<2048, 256, 0, stream>>>(W2, wb, n8);
        gemm_bt<true, _Float16><<<ggrid, 256, 0, stream>>>(h1, wb, b2, h2);
        cvt_f16<<<2048, 256, 0, stream>>>(W3, wb, n8);
        gemm_bt<false, float><<<ggrid, 256, 0, stream>>>(h2, wb, b3, out);
    }
}